// Round 7
// baseline (317.860 us; speedup 1.0000x reference)
//
#include <hip/hip_runtime.h>
#include <hip/hip_cooperative_groups.h>

namespace cg = cooperative_groups;

#define BB 4
#define CC 64
#define HH 112
#define WW 112
#define MD 20
#define KD 41
#define S2 14426.950408f      // (1/TEMP) * log2(e): sims pre-scaled into exp2 domain
#define NPIX (BB*HH*WW)
#define NT 10                 // B quads per row (p = w + dyi in [0,160))
#define ROW2 (NT*2*2*64*8)    // in2s ushorts per (b,row): 20480
#define IN2S_BYTES ((size_t)BB*HH*ROW2*2)   // 18,350,080
#define NEG (-60000.0f)
#define NBLK 256

typedef _Float16 half8   __attribute__((ext_vector_type(8)));
typedef float    f32x4   __attribute__((ext_vector_type(4)));
typedef unsigned short ushort8 __attribute__((ext_vector_type(8)));

static __device__ __forceinline__ float fmax_f(float a, float b) { return a > b ? a : b; }
static __device__ __forceinline__ unsigned short f2h_bits(float x) {
    _Float16 h = (_Float16)x;
    return __builtin_bit_cast(unsigned short, h);
}
static __device__ __forceinline__ float h2f(unsigned short s) {
    return (float)__builtin_bit_cast(_Float16, s);
}
static __device__ __forceinline__ f32x4 vmax4(f32x4 a, f32x4 b) {
    f32x4 r;
    #pragma unroll
    for (int k = 0; k < 4; ++k) r[k] = a[k] > b[k] ? a[k] : b[k];
    return r;
}
static __device__ __forceinline__ f32x4 vexp4(f32x4 d) {
    f32x4 r;
    #pragma unroll
    for (int k = 0; k < 4; ++k) r[k] = __builtin_amdgcn_exp2f(d[k]);
    return r;
}
static __device__ __forceinline__ f32x4 mfma16(half8 a, half8 b, f32x4 c) {
    return __builtin_amdgcn_mfma_f32_16x16x32_f16(a, b, c, 0, 0, 0);
}

// ---- pack one (b,h,tau) unit: wave-level, no LDS ----
static __device__ __forceinline__ void pack_unit(int wid, int lane,
                                                 const float* __restrict__ in2,
                                                 unsigned short* __restrict__ in2s) {
    int tau = wid % NT;
    int bh  = wid / NT;
    int b = bh / HH, h = bh % HH;
    int n = lane & 15, q = lane >> 4;
    int col = 16*tau + n - MD;
    bool ok = (col >= 0 && col < WW);
    const float* src = in2 + ((size_t)(b*CC)*HH + h)*WW + (ok ? col : 0);

    float x[16];
    float ss = 0.f;
    #pragma unroll
    for (int ks = 0; ks < 2; ++ks)
        #pragma unroll
        for (int j = 0; j < 8; ++j) {
            float v = ok ? src[(size_t)(32*ks + 8*q + j)*(HH*WW)] : 0.f;
            x[ks*8 + j] = v;
            ss += v*v;
        }
    ss += __shfl_xor(ss, 16);
    ss += __shfl_xor(ss, 32);
    float iv = 1.0f / fmax_f(__builtin_sqrtf(ss), 1e-12f);

    unsigned short* base = in2s + (size_t)(b*HH + h)*ROW2;
    #pragma unroll
    for (int ks = 0; ks < 2; ++ks) {
        ushort8 hb, lb;
        #pragma unroll
        for (int j = 0; j < 8; ++j) {
            float v = x[ks*8 + j] * iv;
            unsigned short vh = f2h_bits(v);
            hb[j] = vh;
            lb[j] = f2h_bits((v - h2f(vh)) * 4096.0f);
        }
        *(ushort8*)(base + (size_t)((tau*4 + ks*2 + 0)*64 + lane)*8) = hb;
        *(ushort8*)(base + (size_t)((tau*4 + ks*2 + 1)*64 + lane)*8) = lb;
    }
}

// ---- fused kernel: pack -> sync -> corr (2-pixel-tile blocking) -> sync -> merge ----
__global__ __launch_bounds__(512, 2) void fused_kernel(const float* __restrict__ in1,
                                                       const float* __restrict__ in2,
                                                       float* __restrict__ out,
                                                       unsigned short* __restrict__ in2s,
                                                       float* __restrict__ part) {
    cg::grid_group grid = cg::this_grid();
    int blk  = blockIdx.x;             // [0, 256)
    int wv   = threadIdx.x >> 6;       // 0..7
    int lane = threadIdx.x & 63;

    // ================= phase 1: pack (4480 units over 2048 waves) =================
    for (int u = blk*8 + wv; u < BB*HH*NT; u += NBLK*8)
        pack_unit(u, lane, in2, in2s);

    __threadfence();
    grid.sync();

    // ================= phase 2: corr =================
    // slab = (b, h-half) pinned to XCD (blk%8). 672 units/slab = 56 h x 3 g x 4 u.
    {
        int slab = blk & 7;
        int sblk = blk >> 3;           // 0..31
        int b = slab >> 1;
        int n = lane & 15, q = lane >> 4;
        int m0 = 4*q;

        f32x4 NM20; bool v0b[4], v2b[4], v3b[4];
        #pragma unroll
        for (int r = 0; r < 4; ++r) {
            int nm = n - (m0 + r);     // dyi = 16*oi + nm
            NM20[r] = (float)(nm - 20);
            v0b[r] = (nm >= 0);
            v2b[r] = (nm <= 8);
            v3b[r] = (nm <= -8);
        }

        for (int local = sblk*8 + wv; local < 672; local += 256) {
            int hloc = local % 56;
            int rest = local / 56;     // [0,12)
            int g = rest >> 2;         // dx group [0,3)
            int u = rest & 3;          // w-tile pair [0,4); u=3 -> single tile wt=6
            int h = (slab & 1)*56 + hloc;
            int ntile = (u < 3) ? 2 : 1;
            int q0 = 2*u;              // first B quad
            int NQ = (u < 3) ? 5 : 4;  // quads needed

            // ---- A fragments for both tiles (fp16 split, inv-norm in-wave) ----
            half8 aH[2][2], aL[2][2];
            #pragma unroll
            for (int t = 0; t < 2; ++t) {
                if (t >= ntile) break;
                int wA = (q0 + t)*16 + n;
                const float* a_src = in1 + ((size_t)(b*CC)*HH + h)*WW + wA;
                float x[16], ss = 0.f;
                #pragma unroll
                for (int ks = 0; ks < 2; ++ks)
                    #pragma unroll
                    for (int j = 0; j < 8; ++j) {
                        float v = a_src[(size_t)(32*ks + 8*q + j)*(HH*WW)];
                        x[ks*8 + j] = v;
                        ss += v*v;
                    }
                ss += __shfl_xor(ss, 16);
                ss += __shfl_xor(ss, 32);
                float i1 = 1.0f / fmax_f(__builtin_sqrtf(ss), 1e-12f);
                #pragma unroll
                for (int ks = 0; ks < 2; ++ks)
                    #pragma unroll
                    for (int j = 0; j < 8; ++j) {
                        float v = x[ks*8 + j] * i1;
                        _Float16 vh = (_Float16)v;
                        aH[t][ks][j] = vh;
                        aL[t][ks][j] = (_Float16)((v - (float)vh) * 4096.0f);
                    }
            }

            f32x4 SM[2], SL[2], SSX[2], SSY[2];
            #pragma unroll
            for (int t = 0; t < 2; ++t) {
                SM[t] = f32x4{NEG,NEG,NEG,NEG}; SL[t] = f32x4{0.f,0.f,0.f,0.f};
                SSX[t] = f32x4{0.f,0.f,0.f,0.f}; SSY[t] = f32x4{0.f,0.f,0.f,0.f};
            }

            int glo = g*14;
            int ghi = glo + 14 < KD ? glo + 14 : KD;
            int lo = glo > (MD - h) ? glo : (MD - h);
            int hi0 = HH + MD - h;
            int hi = ghi < hi0 ? ghi : hi0;
            if (hi < lo) { lo = ghi; hi = ghi; }

            for (int dxi = lo; dxi < hi; ++dxi) {
                const unsigned short* rb = in2s + (size_t)(b*HH + (h + dxi - MD))*ROW2
                                         + (size_t)q0*2048 + (size_t)lane*8;
                // batch-load all needed quads (5 or 4), 4 frags each
                half8 bq[5][4];
                #pragma unroll
                for (int j = 0; j < 5; ++j) {
                    if (j >= NQ) break;
                    const half8* fp = (const half8*)(rb + (size_t)j*2048);
                    bq[j][0] = fp[0];
                    bq[j][1] = fp[64];
                    bq[j][2] = fp[128];
                    bq[j][3] = fp[192];
                }
                float dxf = (float)(dxi - MD);
                #pragma unroll
                for (int t = 0; t < 2; ++t) {
                    if (t >= ntile) break;
                    f32x4 sv[4];
                    #pragma unroll
                    for (int oi = 0; oi < 4; ++oi) {
                        const half8* f = bq[t + oi];
                        f32x4 a0 = {0.f,0.f,0.f,0.f}, a1 = {0.f,0.f,0.f,0.f};
                        a0 = mfma16(aH[t][0], f[0], a0);
                        a1 = mfma16(aH[t][0], f[1], a1);
                        a1 = mfma16(aL[t][0], f[0], a1);
                        a0 = mfma16(aH[t][1], f[2], a0);
                        a1 = mfma16(aH[t][1], f[3], a1);
                        a1 = mfma16(aL[t][1], f[2], a1);
                        sv[oi] = a0*S2 + a1*(S2/4096.0f);
                    }
                    f32x4 V0, V1 = sv[1], V2, V3;
                    #pragma unroll
                    for (int r = 0; r < 4; ++r) {
                        V0[r] = v0b[r] ? sv[0][r] : NEG;
                        V2[r] = v2b[r] ? sv[2][r] : NEG;
                        V3[r] = v3b[r] ? sv[3][r] : NEG;
                    }
                    f32x4 MN = vmax4(vmax4(SM[t], V0), vmax4(V1, vmax4(V2, V3)));
                    f32x4 ER = vexp4(SM[t] - MN);
                    f32x4 E0 = vexp4(V0 - MN);
                    f32x4 E1 = vexp4(V1 - MN);
                    f32x4 E2 = vexp4(V2 - MN);
                    f32x4 E3 = vexp4(V3 - MN);
                    f32x4 SUM = (E0 + E1) + (E2 + E3);
                    f32x4 TT  = E1 + E2*2.0f + E3*3.0f;
                    SL[t]  = SL[t] *ER + SUM;
                    SSX[t] = SSX[t]*ER + SUM*dxf;
                    SSY[t] = SSY[t]*ER + (TT*16.0f + NM20*SUM);
                    SM[t]  = MN;
                }
            }

            // out-of-image dx rows in this group: all 41 sims exactly 0
            int miss = (lo - glo) + (ghi - hi);
            if (miss > 0) {
                float sdx = 0.f;
                for (int d = glo; d < lo; ++d) sdx += (float)(d - MD);
                for (int d = hi; d < ghi; ++d) sdx += (float)(d - MD);
                float cnt = (float)miss * (float)KD;
                #pragma unroll
                for (int t = 0; t < 2; ++t) {
                    if (t >= ntile) break;
                    f32x4 Z = {0.f,0.f,0.f,0.f};
                    f32x4 MN = vmax4(SM[t], Z);
                    f32x4 ER = vexp4(SM[t] - MN);
                    f32x4 E0 = vexp4(Z - MN);
                    SL[t]  = SL[t] *ER + E0*cnt;
                    SSX[t] = SSX[t]*ER + E0*((float)KD*sdx);
                    SSY[t] = SSY[t]*ER;
                    SM[t]  = MN;
                }
            }

            // butterfly merge across the 16 n-lanes, then write partials
            #pragma unroll
            for (int t = 0; t < 2; ++t) {
                if (t >= ntile) break;
                #pragma unroll
                for (int off = 1; off < 16; off <<= 1) {
                    f32x4 M2, L2, X2, Y2;
                    #pragma unroll
                    for (int k = 0; k < 4; ++k) {
                        M2[k] = __shfl_xor(SM[t][k],  off);
                        L2[k] = __shfl_xor(SL[t][k],  off);
                        X2[k] = __shfl_xor(SSX[t][k], off);
                        Y2[k] = __shfl_xor(SSY[t][k], off);
                    }
                    f32x4 MN = vmax4(SM[t], M2);
                    f32x4 EA = vexp4(SM[t] - MN);
                    f32x4 EB = vexp4(M2 - MN);
                    SL[t]  = SL[t] *EA + L2*EB;
                    SSX[t] = SSX[t]*EA + X2*EB;
                    SSY[t] = SSY[t]*EA + Y2*EB;
                    SM[t]  = MN;
                }
                if (n == 0) {
                    #pragma unroll
                    for (int r = 0; r < 4; ++r) {
                        int w = (q0 + t)*16 + m0 + r;
                        int pix = (b*HH + h)*WW + w;
                        float* p = &part[(size_t)(g*NPIX + pix)*4];
                        p[0] = SM[t][r]; p[1] = SL[t][r]; p[2] = SSX[t][r]; p[3] = SSY[t][r];
                    }
                }
            }
        }
    }

    __threadfence();
    grid.sync();

    // ================= phase 3: merge =================
    for (int idx = blk*512 + (int)threadIdx.x; idx < NPIX; idx += NBLK*512) {
        const float* p0 = &part[(size_t)idx*4];
        const float* p1 = &part[(size_t)(NPIX + idx)*4];
        const float* p2 = &part[(size_t)(2*NPIX + idx)*4];
        float M = fmax_f(fmax_f(p0[0], p1[0]), p2[0]);
        float e0 = __builtin_amdgcn_exp2f(p0[0] - M);
        float e1 = __builtin_amdgcn_exp2f(p1[0] - M);
        float e2 = __builtin_amdgcn_exp2f(p2[0] - M);
        float L  = p0[1]*e0 + p1[1]*e1 + p2[1]*e2;
        float SX = p0[2]*e0 + p1[2]*e1 + p2[2]*e2;
        float SY = p0[3]*e0 + p1[3]*e1 + p2[3]*e2;
        int b = idx / (HH*WW), rem = idx % (HH*WW);
        out[(b*2 + 0)*(HH*WW) + rem] = SX / L;
        out[(b*2 + 1)*(HH*WW) + rem] = SY / L;
    }
}

extern "C" void kernel_launch(void* const* d_in, const int* in_sizes, int n_in,
                              void* d_out, int out_size, void* d_ws, size_t ws_size,
                              hipStream_t stream) {
    const float* in1 = (const float*)d_in[0];
    const float* in2 = (const float*)d_in[1];
    float* out = (float*)d_out;
    unsigned short* in2s = (unsigned short*)d_ws;
    float* part = (float*)((char*)d_ws + IN2S_BYTES);   // [3][NPIX][4]

    void* args[] = { (void*)&in1, (void*)&in2, (void*)&out, (void*)&in2s, (void*)&part };
    hipLaunchCooperativeKernel((void*)fused_kernel, dim3(NBLK), dim3(512),
                               args, 0, stream);
}

// Round 8
// 184.999 us; speedup vs baseline: 1.7182x; 1.7182x over previous
//
#include <hip/hip_runtime.h>

#define BB 4
#define CC 64
#define HH 112
#define WW 112
#define MD 20
#define KD 41
#define S2 14426.950408f      // (1/TEMP) * log2(e): sims pre-scaled into exp2 domain
#define NPIX (BB*HH*WW)
#define NT 10                 // B quads per row (p = w + dyi in [0,160))
#define ROW2 (NT*2*2*64*8)    // in2s ushorts per (b,row): 20480
#define IN2S_BYTES ((size_t)BB*HH*ROW2*2)   // 18,350,080
#define NEG (-60000.0f)
#define MARGIN 32.0f          // scaled skip margin (~0.0022 sim units)

typedef _Float16 half8   __attribute__((ext_vector_type(8)));
typedef float    f32x4   __attribute__((ext_vector_type(4)));
typedef unsigned short ushort8 __attribute__((ext_vector_type(8)));

static __device__ __forceinline__ float fmax_f(float a, float b) { return a > b ? a : b; }
static __device__ __forceinline__ unsigned short f2h_bits(float x) {
    _Float16 h = (_Float16)x;
    return __builtin_bit_cast(unsigned short, h);
}
static __device__ __forceinline__ float h2f(unsigned short s) {
    return (float)__builtin_bit_cast(_Float16, s);
}
static __device__ __forceinline__ f32x4 vmax4(f32x4 a, f32x4 b) {
    f32x4 r;
    #pragma unroll
    for (int k = 0; k < 4; ++k) r[k] = a[k] > b[k] ? a[k] : b[k];
    return r;
}
static __device__ __forceinline__ f32x4 vexp4(f32x4 d) {
    f32x4 r;
    #pragma unroll
    for (int k = 0; k < 4; ++k) r[k] = __builtin_amdgcn_exp2f(d[k]);
    return r;
}
static __device__ __forceinline__ f32x4 mfma16(half8 a, half8 b, f32x4 c) {
    return __builtin_amdgcn_mfma_f32_16x16x32_f16(a, b, c, 0, 0, 0);
}

// ---- pack: block = (b, h, w-side). Coalesced load of a 64ch x 64col slab
// into LDS, in-block column norms, fragment emit for 5 taus x 2 ks. ----
__global__ __launch_bounds__(256) void pack_kernel(const float* __restrict__ in2,
                                                   unsigned short* __restrict__ in2s) {
    __shared__ float tile[CC][65];     // +1 pad
    __shared__ float sinv[64];
    int bid = blockIdx.x;              // [0, 896)
    int side = bid & 1;
    int bh = bid >> 1;
    int b = bh / HH, h = bh % HH;
    int cb = side ? 48 : 0;            // staged col base; side0: cols 0..63, side1: 48..111
    int t = threadIdx.x;
    const float* src = in2 + ((size_t)b*CC*HH + h)*WW;   // + c*HH*WW + col

    for (int i = t; i < CC*64; i += 256) {
        int c = i >> 6, w = i & 63;
        int col = cb + w;
        tile[c][w] = (col < WW) ? src[(size_t)c*(HH*WW) + col] : 0.f;
    }
    __syncthreads();
    if (t < 64) {
        float s = 0.f;
        #pragma unroll
        for (int c = 0; c < CC; ++c) { float x = tile[c][t]; s += x*x; }
        sinv[t] = 1.0f / fmax_f(__builtin_sqrtf(s), 1e-12f);
    }
    __syncthreads();

    int wv = t >> 6, lane = t & 63;
    int n = lane & 15, q = lane >> 4;
    unsigned short* base = in2s + (size_t)bh*ROW2;
    for (int u = wv; u < 10; u += 4) { // (tau-local, ks) units
        int tl = u >> 1, ks = u & 1;
        int tau = 5*side + tl;
        int col = 16*tau + n - MD;
        bool ok = (col >= 0 && col < WW);
        int lc = ok ? (col - cb) : 0;  // local col, clamped when invalid
        float iv = ok ? sinv[lc] : 0.f;
        ushort8 hb, lb;
        #pragma unroll
        for (int j = 0; j < 8; ++j) {
            int c = 32*ks + 8*q + j;
            float x = tile[c][lc] * iv;          // 0 for invalid (iv=0)
            unsigned short xh = f2h_bits(x);
            hb[j] = xh;
            lb[j] = f2h_bits((x - h2f(xh)) * 4096.0f);
        }
        *(ushort8*)(base + (size_t)((tau*4 + ks*2 + 0)*64 + lane)*8) = hb;
        *(ushort8*)(base + (size_t)((tau*4 + ks*2 + 1)*64 + lane)*8) = lb;
    }
}

// ---- corr: round-6 structure + per-oi-tile skip. Hi fragments always
// (8 KB/iter, 8 MFMA); lo refinement + exps only when the tile can matter
// (any sim_hi > pixel-level running max PM - MARGIN). ----
__global__ __launch_bounds__(448) void corr_kernel(const float* __restrict__ in1,
                                                   const unsigned short* __restrict__ in2s,
                                                   float* __restrict__ part) {
    int gid = blockIdx.x;               // [0, 1344)
    int xcd  = gid & 7;                 // XCD slab pinning
    int slot = gid >> 3;                // [0, 168)
    int hloc = slot % 56;
    int g    = slot / 56;               // dx group [0,3)
    int b    = xcd >> 1;
    int h    = (xcd & 1)*56 + hloc;
    int wt   = threadIdx.x >> 6;        // wave = w-tile, 0..6
    int lane = threadIdx.x & 63;
    int n = lane & 15, q = lane >> 4;
    int m0 = 4*q;
    int wA = wt*16 + n;

    // ---- in1 channels; inv1 via q-butterfly; split A fragments ----
    const float* a_src = in1 + ((size_t)(b*CC)*HH + h)*WW + wA;
    float x[16];
    float ss = 0.f;
    #pragma unroll
    for (int ks = 0; ks < 2; ++ks)
        #pragma unroll
        for (int j = 0; j < 8; ++j) {
            float v = a_src[(size_t)(32*ks + 8*q + j)*(HH*WW)];
            x[ks*8 + j] = v;
            ss += v*v;
        }
    ss += __shfl_xor(ss, 16);
    ss += __shfl_xor(ss, 32);
    float i1 = 1.0f / fmax_f(__builtin_sqrtf(ss), 1e-12f);
    half8 aH[2], aL[2];
    #pragma unroll
    for (int ks = 0; ks < 2; ++ks)
        #pragma unroll
        for (int j = 0; j < 8; ++j) {
            float v = x[ks*8 + j] * i1;
            _Float16 vh = (_Float16)v;
            aH[ks][j] = vh;
            aL[ks][j] = (_Float16)((v - (float)vh) * 4096.0f);
        }

    // ---- per-r constants (dyi = 16*oi + n - m) ----
    f32x4 NM20; bool v0b[4], v2b[4], v3b[4];
    #pragma unroll
    for (int r = 0; r < 4; ++r) {
        int nm = n - (m0 + r);
        NM20[r] = (float)(nm - 20);
        v0b[r] = (nm >= 0);
        v2b[r] = (nm <= 8);
        v3b[r] = (nm <= -8);
    }

    f32x4 SM = {NEG,NEG,NEG,NEG}, SL = {0.f,0.f,0.f,0.f};
    f32x4 SSX = {0.f,0.f,0.f,0.f}, SSY = {0.f,0.f,0.f,0.f};
    f32x4 PM = {NEG,NEG,NEG,NEG};       // pixel-level running max (cross-n)

    int glo = g*14;
    int ghi = glo + 14 < KD ? glo + 14 : KD;    // 14,14,13
    int lo = glo > (MD - h) ? glo : (MD - h);
    int hi0 = HH + MD - h;
    int hi = ghi < hi0 ? ghi : hi0;
    if (hi < lo) { lo = ghi; hi = ghi; }

    for (int dxi = lo; dxi < hi; ++dxi) {
        const unsigned short* rb = in2s + (size_t)(b*HH + (h + dxi - MD))*ROW2
                                 + (size_t)lane*8;
        // hi fragments for all 4 oi tiles, batched
        half8 bh0[4], bh1[4];
        #pragma unroll
        for (int oi = 0; oi < 4; ++oi) {
            const half8* fp = (const half8*)(rb + (size_t)(wt + oi)*2048);
            bh0[oi] = fp[0];      // ks0 hi
            bh1[oi] = fp[128];    // ks1 hi
        }
        f32x4 ah[4];
        #pragma unroll
        for (int oi = 0; oi < 4; ++oi) {
            f32x4 a0 = {0.f,0.f,0.f,0.f};
            a0 = mfma16(aH[0], bh0[oi], a0);
            a0 = mfma16(aH[1], bh1[oi], a0);
            ah[oi] = a0 * S2;
        }
        float dxf = (float)(dxi - MD);
        bool anyPass = false;
        #pragma unroll
        for (int oi = 0; oi < 4; ++oi) {
            f32x4 Vh;
            #pragma unroll
            for (int r = 0; r < 4; ++r) {
                bool ok = (oi == 0) ? v0b[r] : (oi == 1) ? true
                        : (oi == 2) ? v2b[r] : v3b[r];
                Vh[r] = ok ? ah[oi][r] : NEG;
            }
            f32x4 d = Vh - PM;
            float tm = fmax_f(fmax_f(d[0], d[1]), fmax_f(d[2], d[3]));
            if (__any(tm > -MARGIN)) {
                anyPass = true;
                const half8* fp = (const half8*)(rb + (size_t)(wt + oi)*2048);
                half8 bl0 = fp[64], bl1 = fp[192];
                f32x4 a1 = {0.f,0.f,0.f,0.f};
                a1 = mfma16(aH[0], bl0, a1);
                a1 = mfma16(aL[0], bh0[oi], a1);
                a1 = mfma16(aH[1], bl1, a1);
                a1 = mfma16(aL[1], bh1[oi], a1);
                f32x4 sv = Vh + a1*(S2/4096.0f);
                f32x4 MN = vmax4(SM, sv);
                f32x4 ER = vexp4(SM - MN);
                f32x4 E  = vexp4(sv - MN);
                float c16 = (float)(16*oi);
                SL  = SL *ER + E;
                SSX = SSX*ER + E*dxf;
                SSY = SSY*ER + E*(NM20 + c16);
                SM  = MN;
            }
        }
        if (anyPass) {   // lazy pixel-max refresh (SM only changes on pass)
            PM = SM;
            #pragma unroll
            for (int off = 1; off < 16; off <<= 1) {
                f32x4 P2;
                #pragma unroll
                for (int k = 0; k < 4; ++k) P2[k] = __shfl_xor(PM[k], off);
                PM = vmax4(PM, P2);
            }
        }
    }

    // out-of-image dx rows in this group: all 41 sims exactly 0 (scaled 0)
    int miss = (lo - glo) + (ghi - hi);
    if (miss > 0) {
        float sdx = 0.f;
        for (int d = glo; d < lo; ++d)  sdx += (float)(d - MD);
        for (int d = hi; d < ghi; ++d)  sdx += (float)(d - MD);
        float cnt = (float)miss * (float)KD;
        f32x4 Z = {0.f,0.f,0.f,0.f};
        f32x4 MN = vmax4(SM, Z);
        f32x4 ER = vexp4(SM - MN);
        f32x4 E0 = vexp4(Z  - MN);
        SL  = SL *ER + E0*cnt;
        SSX = SSX*ER + E0*((float)KD*sdx);
        SSY = SSY*ER;
        SM  = MN;
    }

    // butterfly merge across the 16 n-lanes
    #pragma unroll
    for (int off = 1; off < 16; off <<= 1) {
        f32x4 M2, L2, X2, Y2;
        #pragma unroll
        for (int k = 0; k < 4; ++k) {
            M2[k] = __shfl_xor(SM[k],  off);
            L2[k] = __shfl_xor(SL[k],  off);
            X2[k] = __shfl_xor(SSX[k], off);
            Y2[k] = __shfl_xor(SSY[k], off);
        }
        f32x4 MN = vmax4(SM, M2);
        f32x4 EA = vexp4(SM - MN);
        f32x4 EB = vexp4(M2 - MN);
        SL  = SL *EA + L2*EB;
        SSX = SSX*EA + X2*EB;
        SSY = SSY*EA + Y2*EB;
        SM  = MN;
    }

    if (n == 0) {
        #pragma unroll
        for (int r = 0; r < 4; ++r) {
            int w = wt*16 + m0 + r;
            int pix = (b*HH + h)*WW + w;
            float* p = &part[(size_t)(g*NPIX + pix)*4];
            p[0] = SM[r]; p[1] = SL[r]; p[2] = SSX[r]; p[3] = SSY[r];
        }
    }
}

// ---- merge the 3 dx-group partials (scaled domain), emit flow ----
__global__ __launch_bounds__(256) void merge_kernel(const float* __restrict__ part,
                                                    float* __restrict__ out) {
    int idx = blockIdx.x*256 + threadIdx.x;
    if (idx >= NPIX) return;
    const float* p0 = &part[(size_t)idx*4];
    const float* p1 = &part[(size_t)(NPIX + idx)*4];
    const float* p2 = &part[(size_t)(2*NPIX + idx)*4];
    float M = fmax_f(fmax_f(p0[0], p1[0]), p2[0]);
    float e0 = __builtin_amdgcn_exp2f(p0[0] - M);
    float e1 = __builtin_amdgcn_exp2f(p1[0] - M);
    float e2 = __builtin_amdgcn_exp2f(p2[0] - M);
    float L  = p0[1]*e0 + p1[1]*e1 + p2[1]*e2;
    float SX = p0[2]*e0 + p1[2]*e1 + p2[2]*e2;
    float SY = p0[3]*e0 + p1[3]*e1 + p2[3]*e2;
    int b = idx / (HH*WW), rem = idx % (HH*WW);
    out[(b*2 + 0)*(HH*WW) + rem] = SX / L;
    out[(b*2 + 1)*(HH*WW) + rem] = SY / L;
}

extern "C" void kernel_launch(void* const* d_in, const int* in_sizes, int n_in,
                              void* d_out, int out_size, void* d_ws, size_t ws_size,
                              hipStream_t stream) {
    const float* in1 = (const float*)d_in[0];
    const float* in2 = (const float*)d_in[1];
    float* out = (float*)d_out;
    unsigned short* in2s = (unsigned short*)d_ws;
    float* part = (float*)((char*)d_ws + IN2S_BYTES);   // [3][NPIX][4]

    pack_kernel <<<BB*HH*2, 256, 0, stream>>>(in2, in2s);
    corr_kernel <<<1344, 448, 0, stream>>>(in1, in2s, part);
    merge_kernel<<<(NPIX+255)/256, 256, 0, stream>>>(part, out);
}